// Round 5
// baseline (100.277 us; speedup 1.0000x reference)
//
#include <hip/hip_runtime.h>
#include <math.h>

#define T_WAV   8388608
#define FRAME_L 1024
#define HOP     256
#define NF      32765            // (T_WAV - FRAME_L)/HOP + 1
#define OUT_PB  2048             // outputs per block = 8 hops
#define NBLK    (T_WAV / OUT_PB) // 4096 blocks
#define NTHR    512

// Single fused kernel. Block L covers outputs [2048L, 2048L+2048) = hops
// 8L..8L+7, needing frames [8L-3, 8L+7] -> window of 3584 floats (14 KB) in
// LDS (1.75x read amplification vs 2.5x in R4). Frame params (11 scalars) are
// recomputed in-block by threads 0..10 — removes the prepass launch and the
// d_ws round-trip. XCD swizzle keeps consecutive windows on one XCD's L2.
//
// Mask layout (proven R2-R4): pristine-restore may leave voiced_mask as int32
// 0/1 per frame or packed bool bytes. A byte at (bytelay ? f : 4*f) is correct
// for both (little-endian low byte). Detection: int32 0/1 words never have
// bits in bytes 1..3; packed-bool words do with p=0.992/word — scanning 16
// words gives miss prob 0.008^16 ~ 0.
__global__ __launch_bounds__(512) void psola_fused(
    const float* __restrict__ wav,
    const float* __restrict__ src_f0,
    const float* __restrict__ tgt_f0,
    const unsigned int* __restrict__ mask_words,
    float*       __restrict__ out)
{
    __shared__ float s_wav[3588];    // 3584 window + pad for x0==1023 pair-read
    __shared__ float s_scl[11];
    __shared__ int   s_enc[11];

    const int p   = blockIdx.x;
    const int L   = ((p & 7) << 9) + (p >> 3);   // XCD-aware swizzle (4096 = 8*512)
    const int tid = threadIdx.x;
    const int tl  = tid & 255;
    const int th  = tid >> 8;                    // wave-uniform (0 or 1)

    const int b0   = L << 3;                     // first hop index
    const int B    = L << 11;                    // first output sample
    const int f0   = (b0 > 3) ? (b0 - 3) : 0;
    const int f1   = ((b0 + 7) < NF - 1) ? (b0 + 7) : (NF - 1);
    const int base = f0 << 8;
    const int wlen = ((f1 - f0) << 8) + 1024;    // <= 3584, mult of 4

    // ---- stage wav window (coalesced float4; base 1 KiB aligned, end <= T_WAV)
    {
        const float4* g4 = (const float4*)(wav + base);
        float4*       s4 = (float4*)s_wav;
        const int nv = wlen >> 2;                // <= 896
        for (int i = tid; i < nv; i += NTHR) s4[i] = g4[i];
    }
    if (tid == 0) s_wav[wlen] = 0.0f;

    // ---- per-frame params, computed by threads 0..(f1-f0)
    const int nfr = f1 - f0 + 1;                 // <= 11
    if (tid < nfr) {
        bool bytelay = false;
        #pragma unroll
        for (int i = 0; i < 16; ++i) {
            unsigned w = mask_words[i];
            if ((w & 0xFFFFFF00u) != 0u && w != 0xFFFFFFFFu) bytelay = true;
        }
        const int f = f0 + tid;
        float src = src_f0[f];
        float tgt = tgt_f0[f];
        const unsigned char* m8 = (const unsigned char*)mask_words;
        unsigned off = bytelay ? (unsigned)f : ((unsigned)f << 2);
        bool valid = (m8[off] != 0) && (src >= 1.0f) && (tgt >= 1.0f);
        float denom = (tgt >= 1.0f) ? tgt : 1.0f;
        float ratio = fminf(fmaxf(src / denom, 0.25f), 4.0f);
        int nl = (int)rintf(1024.0f * ratio);    // round-half-even == jnp.round
        if (nl < 1) nl = 1;
        s_scl[tid] = 1024.0f / (float)nl;
        s_enc[tid] = valid ? nl : -1;
    }

    // ---- hann values this thread ever needs: j = tl + 256*m, m=0..3
    float hh[4], jf[4];
    #pragma unroll
    for (int m = 0; m < 4; ++m) {
        int j = tl + (m << 8);
        hh[m] = 0.5f - 0.5f * cospif((float)j * (1.0f / 512.0f));
        jf[m] = (float)j + 0.5f;
    }
    float wsum4 = hh[0] + hh[1] + hh[2] + hh[3]; // == 2.0 up to fp rounding
    float rw4   = (wsum4 > 1e-8f) ? (1.0f / wsum4) : 1.0f;

    __syncthreads();

    if (f0 == b0 - 3 && (b0 + 7) <= NF - 1) {
        // interior: every output has exactly 4 covering frames
        #pragma unroll
        for (int k = 0; k < 4; ++k) {
            const int c     = (k << 1) + th;         // hop within block, 0..7
            const int loc_t = (c << 8) + tl + 768;   // index of t in s_wav
            float acc = 0.0f;
            #pragma unroll
            for (int q = 0; q < 4; ++q) {
                const int fi = c + q;                // frame f0+fi (wave-uniform)
                const int m  = 3 - q;                // j = tl + m*256
                const int e  = s_enc[fi];
                float val;
                if (e < 0) {
                    val = s_wav[loc_t];              // unvoiced: original sample
                } else if ((tl + (m << 8)) < e) {
                    float s  = s_scl[fi];
                    float x  = fminf(fmaxf(fmaf(jf[m], s, -0.5f), 0.0f), 1023.0f);
                    int   x0 = (int)x;
                    float w2 = x - (float)x0;
                    const float* pp = &s_wav[(fi << 8) + x0];
                    float v0 = pp[0];
                    float v1 = pp[1];                // pad-safe; w2==0 at edge
                    val = fmaf(w2, v1 - v0, v0);
                } else {
                    val = 0.0f;
                }
                acc = fmaf(val, hh[m], acc);
            }
            __builtin_nontemporal_store(acc * rw4, &out[B + (k << 9) + tid]);
        }
    } else {
        // edge blocks (L==0, L==NBLK-1): generic clamped frame loop
        for (int k = 0; k < 4; ++k) {
            const int t  = B + (k << 9) + tid;
            const int bt = t >> 8;
            int lo = bt - 3; if (lo < 0) lo = 0;
            int hi = bt;     if (hi > NF - 1) hi = NF - 1;
            float acc = 0.0f, wsum = 0.0f;
            for (int f = lo; f <= hi; ++f) {
                const int fi = f - f0;
                const int j  = t - (f << 8);
                const int m  = j >> 8;
                const float h = hh[m];
                const int   e = s_enc[fi];
                float val;
                if (e < 0) {
                    val = s_wav[t - base];
                } else if (j < e) {
                    float s  = s_scl[fi];
                    float x  = fminf(fmaxf(fmaf(jf[m], s, -0.5f), 0.0f), 1023.0f);
                    int   x0 = (int)x;
                    float w2 = x - (float)x0;
                    const float* pp = &s_wav[(fi << 8) + x0];
                    float v0 = pp[0];
                    float v1 = pp[1];
                    val = fmaf(w2, v1 - v0, v0);
                } else {
                    val = 0.0f;
                }
                acc  = fmaf(val, h, acc);
                wsum += h;
            }
            float o = (wsum > 1e-8f) ? (acc / wsum) : acc;
            __builtin_nontemporal_store(o, &out[t]);
        }
    }
}

extern "C" void kernel_launch(void* const* d_in, const int* in_sizes, int n_in,
                              void* d_out, int out_size, void* d_ws, size_t ws_size,
                              hipStream_t stream) {
    const float*        wav  = (const float*)d_in[0];
    const float*        src  = (const float*)d_in[1];
    const float*        tgt  = (const float*)d_in[2];
    const unsigned int* mask = (const unsigned int*)d_in[3];
    float*              out  = (float*)d_out;

    psola_fused<<<NBLK, NTHR, 0, stream>>>(wav, src, tgt, mask, out);
}

// Round 6
// 98.383 us; speedup vs baseline: 1.0192x; 1.0192x over previous
//
#include <hip/hip_runtime.h>
#include <math.h>

#define T_WAV   8388608
#define FRAME_L 1024
#define HOP     256
#define NF      32765            // (T_WAV - FRAME_L)/HOP + 1
#define OUT_PB  2048             // outputs per block = 8 hops
#define NBLK    (T_WAV / OUT_PB) // 4096 blocks
#define NTHR    256              // each thread produces 8 outputs (one per hop)

// Single fused kernel. Block L covers outputs [2048L, 2048L+2048) = hops
// 8L..8L+7, needing frames [8L-3, 8L+7] -> window of 3584 floats (14 KB) in
// LDS. KEY CHANGE vs R5: 256 threads x 8 outputs each, so the hop index k is
// a compile-time constant after unrolling -> frame index fi = k+q is a
// LITERAL -> enc_r[]/scl_r[] promote to named VGPRs (R3-R5 had VGPR_Count=8:
// params were re-read from LDS in every inner iteration).
//
// Mask layout (proven R2-R5): pristine-restore may leave voiced_mask as int32
// 0/1 per frame or packed bool bytes. A byte at (bytelay ? f : 4*f) is
// correct for both (little-endian low byte). int32 0/1 words never have bits
// in bytes 1..3; packed-bool words do with p=0.992/word -> scanning 16 words
// gives miss prob 0.008^16 ~ 0.
__global__ __launch_bounds__(256, 6) void psola_fused(
    const float* __restrict__ wav,
    const float* __restrict__ src_f0,
    const float* __restrict__ tgt_f0,
    const unsigned int* __restrict__ mask_words,
    float*       __restrict__ out)
{
    __shared__ float s_wav[3588];    // 3584 window + pad for x0==1023 pair-read
    __shared__ float s_scl[11];
    __shared__ int   s_enc[11];

    const int p   = blockIdx.x;
    const int L   = ((p & 7) << 9) + (p >> 3);   // XCD swizzle (4096 = 8*512)
    const int tid = threadIdx.x;

    const int b0   = L << 3;                     // first hop index
    const int B    = L << 11;                    // first output sample
    const int f0   = (b0 > 3) ? (b0 - 3) : 0;
    const int f1   = ((b0 + 7) < NF - 1) ? (b0 + 7) : (NF - 1);
    const int base = f0 << 8;
    const int wlen = ((f1 - f0) << 8) + 1024;    // <= 3584, mult of 4

    // ---- stage wav window (coalesced float4; base 1 KiB aligned, end <= T_WAV)
    {
        const float4* g4 = (const float4*)(wav + base);
        float4*       s4 = (float4*)s_wav;
        const int nv = wlen >> 2;                // <= 896
        #pragma unroll
        for (int i = 0; i < 4; ++i) {
            int idx = tid + (i << 8);
            if (idx < nv) s4[idx] = g4[idx];
        }
    }
    if (tid == 0) s_wav[wlen] = 0.0f;

    // ---- per-frame params, threads 0..10
    if (tid < 11) {
        bool bytelay = false;
        #pragma unroll
        for (int i = 0; i < 16; ++i) {
            unsigned w = mask_words[i];
            if ((w & 0xFFFFFF00u) != 0u && w != 0xFFFFFFFFu) bytelay = true;
        }
        const int f = f0 + tid;
        if (f <= f1) {
            float src = src_f0[f];
            float tgt = tgt_f0[f];
            const unsigned char* m8 = (const unsigned char*)mask_words;
            unsigned off = bytelay ? (unsigned)f : ((unsigned)f << 2);
            bool valid = (m8[off] != 0) && (src >= 1.0f) && (tgt >= 1.0f);
            float denom = (tgt >= 1.0f) ? tgt : 1.0f;
            float ratio = fminf(fmaxf(src / denom, 0.25f), 4.0f);
            int nl = (int)rintf(1024.0f * ratio);   // round-half-even == jnp.round
            if (nl < 1) nl = 1;
            s_scl[tid] = 1024.0f / (float)nl;
            s_enc[tid] = valid ? nl : -1;
        } else {
            s_scl[tid] = 1.0f;
            s_enc[tid] = -1;
        }
    }

    // ---- hann values this thread ever needs: j = tid + 256*m, m=0..3
    float hh[4], jf[4];
    #pragma unroll
    for (int m = 0; m < 4; ++m) {
        int j = tid + (m << 8);
        hh[m] = 0.5f - 0.5f * cospif((float)j * (1.0f / 512.0f));
        jf[m] = (float)j + 0.5f;
    }
    float wsum4 = hh[0] + hh[1] + hh[2] + hh[3]; // == 2.0 up to fp rounding
    float rw4   = (wsum4 > 1e-8f) ? (1.0f / wsum4) : 1.0f;

    __syncthreads();

    if (f0 == b0 - 3 && (b0 + 7) <= NF - 1) {
        // interior: params into registers (literal indices after unroll)
        int   enc_r[11];
        float scl_r[11];
        #pragma unroll
        for (int i = 0; i < 11; ++i) { enc_r[i] = s_enc[i]; scl_r[i] = s_scl[i]; }

        #pragma unroll
        for (int k = 0; k < 8; ++k) {                 // hop k (literal)
            const float wt  = s_wav[(k << 8) + tid + 768];  // unvoiced sample
            float acc = 0.0f;
            #pragma unroll
            for (int q = 0; q < 4; ++q) {
                const int fi = k + q;                 // LITERAL frame index
                const int m  = 3 - q;                 // j = tid + m*256
                const int e  = enc_r[fi];
                const int j  = tid + (m << 8);
                float val;
                if (e < 0) {
                    val = wt;
                } else if (j < e) {
                    float s  = scl_r[fi];
                    float x  = fminf(fmaxf(fmaf(jf[m], s, -0.5f), 0.0f), 1023.0f);
                    int   x0 = (int)x;
                    float w2 = x - (float)x0;
                    const float* pp = &s_wav[(fi << 8) + x0];
                    float v0 = pp[0];
                    float v1 = pp[1];                 // pad-safe; w2==0 at edge
                    val = fmaf(w2, v1 - v0, v0);
                } else {
                    val = 0.0f;
                }
                acc = fmaf(val, hh[m], acc);
            }
            __builtin_nontemporal_store(acc * rw4, &out[B + (k << 8) + tid]);
        }
    } else {
        // edge blocks (L==0, L==NBLK-1 only): generic clamped frame loop
        for (int k = 0; k < 8; ++k) {
            const int t  = B + (k << 8) + tid;
            const int bt = t >> 8;
            int lo = bt - 3; if (lo < 0) lo = 0;
            int hi = bt;     if (hi > NF - 1) hi = NF - 1;
            float acc = 0.0f, wsum = 0.0f;
            for (int f = lo; f <= hi; ++f) {
                const int fi = f - f0;
                const int j  = t - (f << 8);
                const int m  = j >> 8;
                const float h = hh[m];
                const int   e = s_enc[fi];
                float val;
                if (e < 0) {
                    val = s_wav[t - base];
                } else if (j < e) {
                    float s  = s_scl[fi];
                    float x  = fminf(fmaxf(fmaf((float)j + 0.5f, s, -0.5f), 0.0f), 1023.0f);
                    int   x0 = (int)x;
                    float w2 = x - (float)x0;
                    const float* pp = &s_wav[(fi << 8) + x0];
                    val = fmaf(w2, pp[1] - pp[0], pp[0]);
                } else {
                    val = 0.0f;
                }
                acc  = fmaf(val, h, acc);
                wsum += h;
            }
            float o = (wsum > 1e-8f) ? (acc / wsum) : acc;
            __builtin_nontemporal_store(o, &out[t]);
        }
    }
}

extern "C" void kernel_launch(void* const* d_in, const int* in_sizes, int n_in,
                              void* d_out, int out_size, void* d_ws, size_t ws_size,
                              hipStream_t stream) {
    const float*        wav  = (const float*)d_in[0];
    const float*        src  = (const float*)d_in[1];
    const float*        tgt  = (const float*)d_in[2];
    const unsigned int* mask = (const unsigned int*)d_in[3];
    float*              out  = (float*)d_out;

    psola_fused<<<NBLK, NTHR, 0, stream>>>(wav, src, tgt, mask, out);
}